// Round 1
// baseline (4705.161 us; speedup 1.0000x reference)
//
#include <hip/hip_runtime.h>
#include <math.h>

#define N_NODES 100000
#define N_IN 512
#define N_H 256
#define N_OUT 64
#define KHOP 10
#define EPS_BN 1e-5f
#define INV_TEMP (1.0f/1.5f)

// ---------------- CSR build ----------------

__global__ void init_kernel(int* __restrict__ deg, int* __restrict__ cursor, int n) {
    int i = blockIdx.x * blockDim.x + threadIdx.x;
    if (i < n) { deg[i] = 1; cursor[i] = 0; }   // deg starts at 1 for the self loop
}

__global__ void count_kernel(const int* __restrict__ ei, int* __restrict__ deg, int E) {
    int i = blockIdx.x * blockDim.x + threadIdx.x;
    if (i < E) atomicAdd(&deg[ei[i]], 1);
}

// block = 256 threads, each handles 4 elems -> 1024 per block
__global__ void scan1_kernel(const int* __restrict__ deg, int* __restrict__ excl,
                             int* __restrict__ bsum, int n) {
    __shared__ int sd[256];
    int t = threadIdx.x;
    int base = blockIdx.x * 1024 + t * 4;
    int v0 = (base + 0 < n) ? deg[base + 0] : 0;
    int v1 = (base + 1 < n) ? deg[base + 1] : 0;
    int v2 = (base + 2 < n) ? deg[base + 2] : 0;
    int v3 = (base + 3 < n) ? deg[base + 3] : 0;
    int tot = v0 + v1 + v2 + v3;
    sd[t] = tot;
    __syncthreads();
    for (int off = 1; off < 256; off <<= 1) {
        int x = (t >= off) ? sd[t - off] : 0;
        __syncthreads();
        sd[t] += x;
        __syncthreads();
    }
    int run = sd[t] - tot;   // exclusive
    if (t == 255) bsum[blockIdx.x] = sd[t];
    if (base + 0 < n) excl[base + 0] = run; run += v0;
    if (base + 1 < n) excl[base + 1] = run; run += v1;
    if (base + 2 < n) excl[base + 2] = run; run += v2;
    if (base + 3 < n) excl[base + 3] = run;
}

__global__ void scan2_kernel(int* __restrict__ bsum, int nb) {
    __shared__ int sd[128];
    int t = threadIdx.x;
    int v = (t < nb) ? bsum[t] : 0;
    sd[t] = v;
    __syncthreads();
    for (int off = 1; off < 128; off <<= 1) {
        int x = (t >= off) ? sd[t - off] : 0;
        __syncthreads();
        sd[t] += x;
        __syncthreads();
    }
    if (t < nb) bsum[t] = sd[t] - v;   // exclusive
}

__global__ void scan3_kernel(int* __restrict__ row_ptr, const int* __restrict__ bsum,
                             const int* __restrict__ deg, float* __restrict__ dinv,
                             int n, int total) {
    int i = blockIdx.x * blockDim.x + threadIdx.x;
    if (i < n) {
        row_ptr[i] += bsum[i >> 10];
        dinv[i] = rsqrtf((float)deg[i]);
    }
    if (i == 0) row_ptr[n] = total;
}

__global__ void fill_kernel(const int* __restrict__ ei, int* __restrict__ cursor,
                            const int* __restrict__ row_ptr, const float* __restrict__ dinv,
                            int* __restrict__ colv, float* __restrict__ val, int E, int n) {
    int i = blockIdx.x * blockDim.x + threadIdx.x;
    if (i >= E + n) return;
    int r, c;
    if (i < E) { r = ei[i]; c = ei[E + i]; }
    else       { r = i - E; c = r; }
    int pos = row_ptr[r] + atomicAdd(&cursor[r], 1);
    colv[pos] = c;
    val[pos] = dinv[c];
}

// ---------------- GEMM (fp32, 64x64 tile, 16-deep K slices) ----------------

#define TILE_M 64
#define TILE_N 64
#define TILE_K 16

template<int KDIM, int NDIM>
__global__ __launch_bounds__(256) void gemm_bias_kernel(
    const float* __restrict__ A, const float* __restrict__ W,
    const float* __restrict__ bias, float* __restrict__ C, int M) {
    __shared__ float As[TILE_K][TILE_M + 1];
    __shared__ float Bs[TILE_K][TILE_N + 4];
    int t = threadIdx.x;
    int mbase = blockIdx.y * TILE_M;
    int nbase = blockIdx.x * TILE_N;
    int tm = (t >> 4) << 2;   // 0..60
    int tn = (t & 15) << 2;   // 0..60
    int ar = t >> 2;          // 0..63
    int ac = (t & 3) << 2;    // 0,4,8,12
    int br = t >> 4;          // 0..15
    int bc = (t & 15) << 2;   // 0..60
    float acc[4][4] = {};
    for (int k0 = 0; k0 < KDIM; k0 += TILE_K) {
        float4 av;
        int arow = mbase + ar;
        if (arow < M) av = *reinterpret_cast<const float4*>(&A[(size_t)arow * KDIM + k0 + ac]);
        else av = make_float4(0.f, 0.f, 0.f, 0.f);
        As[ac + 0][ar] = av.x; As[ac + 1][ar] = av.y;
        As[ac + 2][ar] = av.z; As[ac + 3][ar] = av.w;
        float4 bv = *reinterpret_cast<const float4*>(&W[(size_t)(k0 + br) * NDIM + nbase + bc]);
        *reinterpret_cast<float4*>(&Bs[br][bc]) = bv;
        __syncthreads();
#pragma unroll
        for (int kk = 0; kk < TILE_K; ++kk) {
            float a0 = As[kk][tm + 0], a1 = As[kk][tm + 1];
            float a2 = As[kk][tm + 2], a3 = As[kk][tm + 3];
            float b0 = Bs[kk][tn + 0], b1 = Bs[kk][tn + 1];
            float b2 = Bs[kk][tn + 2], b3 = Bs[kk][tn + 3];
            acc[0][0] += a0 * b0; acc[0][1] += a0 * b1; acc[0][2] += a0 * b2; acc[0][3] += a0 * b3;
            acc[1][0] += a1 * b0; acc[1][1] += a1 * b1; acc[1][2] += a1 * b2; acc[1][3] += a1 * b3;
            acc[2][0] += a2 * b0; acc[2][1] += a2 * b1; acc[2][2] += a2 * b2; acc[2][3] += a2 * b3;
            acc[3][0] += a3 * b0; acc[3][1] += a3 * b1; acc[3][2] += a3 * b2; acc[3][3] += a3 * b3;
        }
        __syncthreads();
    }
#pragma unroll
    for (int i = 0; i < 4; ++i) {
        int row = mbase + tm + i;
        if (row < M) {
#pragma unroll
            for (int j = 0; j < 4; ++j) {
                int col = nbase + tn + j;
                C[(size_t)row * NDIM + col] = acc[i][j] + bias[col];
            }
        }
    }
}

// ---------------- BatchNorm stats + apply ----------------

__global__ void colstats_kernel(const float* __restrict__ T, float* __restrict__ sums, int M) {
    int col = threadIdx.x;               // 256 columns
    int r0 = blockIdx.x * 256;
    int r1 = min(r0 + 256, M);
    float s = 0.f, s2 = 0.f;
    for (int r = r0; r < r1; ++r) {
        float v = T[(size_t)r * N_H + col];
        s += v; s2 += v * v;
    }
    atomicAdd(&sums[col], s);
    atomicAdd(&sums[N_H + col], s2);
}

__global__ void finalize_stats_kernel(const float* __restrict__ sums,
                                      const float* __restrict__ g, const float* __restrict__ be,
                                      float* __restrict__ ab, float invM) {
    int c = threadIdx.x;
    float mean = sums[c] * invM;
    float var = sums[N_H + c] * invM - mean * mean;
    float a = g[c] * rsqrtf(var + EPS_BN);
    ab[c] = a;
    ab[N_H + c] = be[c] - mean * a;
}

__global__ void bn_gelu_kernel(const float* __restrict__ T, const float* __restrict__ ab,
                               const float* __restrict__ res, float* __restrict__ Y, int total) {
    int i = blockIdx.x * blockDim.x + threadIdx.x;
    if (i >= total) return;
    int c = i & (N_H - 1);
    float v = ab[c] * T[i] + ab[N_H + c];
    if (res) v += res[i];
    Y[i] = 0.5f * v * (1.f + erff(v * 0.70710678118654752f));
}

// ---------------- Propagation ----------------

__global__ void prop_init_kernel(const float* __restrict__ h, const float* __restrict__ alpha,
                                 float* __restrict__ out, int total) {
    int i = blockIdx.x * blockDim.x + threadIdx.x;
    if (i < total) out[i] = h[i] * (alpha[0] * INV_TEMP);
}

// one wave per row, lane = feature (OUT=64)
__global__ __launch_bounds__(256) void prop_kernel(
    const float* __restrict__ xin, float* __restrict__ xout,
    const int* __restrict__ colv, const float* __restrict__ val,
    const int* __restrict__ row_ptr, const float* __restrict__ dinv,
    float* __restrict__ acc, const float* __restrict__ alpha, int kidx, int n) {
    int r = (blockIdx.x << 2) + (threadIdx.x >> 6);
    if (r >= n) return;
    int lane = threadIdx.x & 63;
    int s = row_ptr[r], e = row_ptr[r + 1];
    float sum = 0.f;
    for (int i = s; i < e; ++i) {
        sum += val[i] * xin[((size_t)colv[i] << 6) + lane];
    }
    float res = dinv[r] * sum;
    int o = (r << 6) + lane;
    xout[o] = res;
    acc[o] += (alpha[kidx] * INV_TEMP) * res;
}

// ---------------- Host ----------------

extern "C" void kernel_launch(void* const* d_in, const int* in_sizes, int n_in,
                              void* d_out, int out_size, void* d_ws, size_t ws_size,
                              hipStream_t stream) {
    const float* x    = (const float*)d_in[0];
    const int*   ei   = (const int*)d_in[1];
    const float* w1   = (const float*)d_in[2];
    const float* b1   = (const float*)d_in[3];
    const float* g1   = (const float*)d_in[4];
    const float* be1  = (const float*)d_in[5];
    const float* w2   = (const float*)d_in[6];
    const float* b2   = (const float*)d_in[7];
    const float* g2   = (const float*)d_in[8];
    const float* be2  = (const float*)d_in[9];
    const float* w3   = (const float*)d_in[10];
    const float* b3   = (const float*)d_in[11];
    const float* g3   = (const float*)d_in[12];
    const float* be3  = (const float*)d_in[13];
    const float* w4   = (const float*)d_in[14];
    const float* b4   = (const float*)d_in[15];
    const float* alpha= (const float*)d_in[16];
    float* out = (float*)d_out;

    const int N = in_sizes[0] / N_IN;     // 100000
    const int E = in_sizes[1] / 2;        // 3200000
    const int EN = E + N;

    // workspace carve-up (256B aligned)
    char* ws = (char*)d_ws;
    size_t off = 0;
    auto alloc = [&](size_t bytes) -> void* {
        void* p = ws + off;
        off = (off + bytes + 255) & ~(size_t)255;
        return p;
    };
    int*   deg     = (int*)alloc((size_t)N * 4);
    int*   cursor  = (int*)alloc((size_t)N * 4);
    int*   row_ptr = (int*)alloc((size_t)(N + 1) * 4);
    float* dinv    = (float*)alloc((size_t)N * 4);
    int*   colv    = (int*)alloc((size_t)EN * 4);
    float* val     = (float*)alloc((size_t)EN * 4);
    int*   bsum    = (int*)alloc(128 * 4);
    float* sums    = (float*)alloc(2 * N_H * 4);
    float* ab      = (float*)alloc(2 * N_H * 4);
    float* T       = (float*)alloc((size_t)N * N_H * 4);   // pre-BN GEMM out; later reused as xt0/xt1
    float* Abuf    = (float*)alloc((size_t)N * N_H * 4);   // x0, then x2
    float* Bbuf    = (float*)alloc((size_t)N * N_H * 4);   // x1, then h
    // aliases (T free after GEMM4; Bbuf holds h)
    float* hbuf = Bbuf;
    float* xt0  = T;
    float* xt1  = T + (size_t)N * N_OUT;

    const int TB = 256;
    int nbN  = (N + TB - 1) / TB;
    int nbE  = (E + TB - 1) / TB;
    int nbEN = (EN + TB - 1) / TB;
    int nscan = (N + 1023) / 1024;

    // --- CSR build ---
    init_kernel<<<nbN, TB, 0, stream>>>(deg, cursor, N);
    count_kernel<<<nbE, TB, 0, stream>>>(ei, deg, E);
    scan1_kernel<<<nscan, TB, 0, stream>>>(deg, row_ptr, bsum, N);
    scan2_kernel<<<1, 128, 0, stream>>>(bsum, nscan);
    scan3_kernel<<<nbN, TB, 0, stream>>>(row_ptr, bsum, deg, dinv, N, EN);
    fill_kernel<<<nbEN, TB, 0, stream>>>(ei, cursor, row_ptr, dinv, colv, val, E, N);

    int mt = (N + TILE_M - 1) / TILE_M;
    int elemH = N * N_H;
    int nbElemH = (elemH + TB - 1) / TB;
    int nbStats = (N + 255) / 256;

    // --- layer 1 ---
    gemm_bias_kernel<N_IN, N_H><<<dim3(N_H / TILE_N, mt), TB, 0, stream>>>(x, w1, b1, T, N);
    hipMemsetAsync(sums, 0, 2 * N_H * 4, stream);
    colstats_kernel<<<nbStats, N_H, 0, stream>>>(T, sums, N);
    finalize_stats_kernel<<<1, N_H, 0, stream>>>(sums, g1, be1, ab, 1.0f / N);
    bn_gelu_kernel<<<nbElemH, TB, 0, stream>>>(T, ab, nullptr, Abuf, elemH);
    // --- layer 2 ---
    gemm_bias_kernel<N_H, N_H><<<dim3(N_H / TILE_N, mt), TB, 0, stream>>>(Abuf, w2, b2, T, N);
    hipMemsetAsync(sums, 0, 2 * N_H * 4, stream);
    colstats_kernel<<<nbStats, N_H, 0, stream>>>(T, sums, N);
    finalize_stats_kernel<<<1, N_H, 0, stream>>>(sums, g2, be2, ab, 1.0f / N);
    bn_gelu_kernel<<<nbElemH, TB, 0, stream>>>(T, ab, Abuf, Bbuf, elemH);
    // --- layer 3 ---
    gemm_bias_kernel<N_H, N_H><<<dim3(N_H / TILE_N, mt), TB, 0, stream>>>(Bbuf, w3, b3, T, N);
    hipMemsetAsync(sums, 0, 2 * N_H * 4, stream);
    colstats_kernel<<<nbStats, N_H, 0, stream>>>(T, sums, N);
    finalize_stats_kernel<<<1, N_H, 0, stream>>>(sums, g3, be3, ab, 1.0f / N);
    bn_gelu_kernel<<<nbElemH, TB, 0, stream>>>(T, ab, Bbuf, Abuf, elemH);
    // --- layer 4 (h = x2 @ w4 + b4) ---
    gemm_bias_kernel<N_H, N_OUT><<<dim3(N_OUT / TILE_N, mt), TB, 0, stream>>>(Abuf, w4, b4, hbuf, N);

    // --- propagation ---
    int elemO = N * N_OUT;
    int nbElemO = (elemO + TB - 1) / TB;
    prop_init_kernel<<<nbElemO, TB, 0, stream>>>(hbuf, alpha, out, elemO);

    const float* cur = hbuf;
    float* pa = xt0;
    float* pb = xt1;
    int nbProp = (N + 3) / 4;
    for (int k = 1; k <= KHOP; ++k) {
        prop_kernel<<<nbProp, TB, 0, stream>>>(cur, pa, colv, val, row_ptr, dinv,
                                               out, alpha, k, N);
        cur = pa;
        float* tmp = pa; pa = pb; pb = tmp;
    }
}

// Round 2
// 2352.730 us; speedup vs baseline: 1.9999x; 1.9999x over previous
//
#include <hip/hip_runtime.h>
#include <math.h>

#define N_NODES 100000
#define N_IN 512
#define N_H 256
#define N_OUT 64
#define KHOP 10
#define EPS_BN 1e-5f
#define INV_TEMP (1.0f/1.5f)

using half8  = __attribute__((ext_vector_type(8))) _Float16;
using half4  = __attribute__((ext_vector_type(4))) _Float16;
using floatx4 = __attribute__((ext_vector_type(4))) float;

// ---------------- CSR build ----------------

__global__ void init_kernel(int* __restrict__ deg, int* __restrict__ cursor, int n) {
    int i = blockIdx.x * blockDim.x + threadIdx.x;
    if (i < n) { deg[i] = 1; cursor[i] = 0; }   // deg starts at 1 for the self loop
}

__global__ void count_kernel(const int* __restrict__ ei, int* __restrict__ deg, int E) {
    int i = blockIdx.x * blockDim.x + threadIdx.x;
    if (i < E) atomicAdd(&deg[ei[i]], 1);
}

// block = 256 threads, each handles 4 elems -> 1024 per block
__global__ void scan1_kernel(const int* __restrict__ deg, int* __restrict__ excl,
                             int* __restrict__ bsum, int n) {
    __shared__ int sd[256];
    int t = threadIdx.x;
    int base = blockIdx.x * 1024 + t * 4;
    int v0 = (base + 0 < n) ? deg[base + 0] : 0;
    int v1 = (base + 1 < n) ? deg[base + 1] : 0;
    int v2 = (base + 2 < n) ? deg[base + 2] : 0;
    int v3 = (base + 3 < n) ? deg[base + 3] : 0;
    int tot = v0 + v1 + v2 + v3;
    sd[t] = tot;
    __syncthreads();
    for (int off = 1; off < 256; off <<= 1) {
        int x = (t >= off) ? sd[t - off] : 0;
        __syncthreads();
        sd[t] += x;
        __syncthreads();
    }
    int run = sd[t] - tot;   // exclusive
    if (t == 255) bsum[blockIdx.x] = sd[t];
    if (base + 0 < n) excl[base + 0] = run; run += v0;
    if (base + 1 < n) excl[base + 1] = run; run += v1;
    if (base + 2 < n) excl[base + 2] = run; run += v2;
    if (base + 3 < n) excl[base + 3] = run;
}

__global__ void scan2_kernel(int* __restrict__ bsum, int nb) {
    __shared__ int sd[128];
    int t = threadIdx.x;
    int v = (t < nb) ? bsum[t] : 0;
    sd[t] = v;
    __syncthreads();
    for (int off = 1; off < 128; off <<= 1) {
        int x = (t >= off) ? sd[t - off] : 0;
        __syncthreads();
        sd[t] += x;
        __syncthreads();
    }
    if (t < nb) bsum[t] = sd[t] - v;   // exclusive
}

__global__ void scan3_kernel(int* __restrict__ row_ptr, const int* __restrict__ bsum,
                             const int* __restrict__ deg, float* __restrict__ dinv,
                             int n, int total) {
    int i = blockIdx.x * blockDim.x + threadIdx.x;
    if (i < n) {
        row_ptr[i] += bsum[i >> 10];
        dinv[i] = rsqrtf((float)deg[i]);
    }
    if (i == 0) row_ptr[n] = total;
}

__global__ void fill_kernel(const int* __restrict__ ei, int* __restrict__ cursor,
                            const int* __restrict__ row_ptr, const float* __restrict__ dinv,
                            int2* __restrict__ ep, int E, int n) {
    int i = blockIdx.x * blockDim.x + threadIdx.x;
    if (i >= E + n) return;
    int r, c;
    if (i < E) { r = ei[i]; c = ei[E + i]; }
    else       { r = i - E; c = r; }
    int pos = row_ptr[r] + atomicAdd(&cursor[r], 1);
    ep[pos] = make_int2(c, __float_as_int(dinv[c]));
}

// ---------------- conversions ----------------

__global__ void cvt_f16_kernel(const float* __restrict__ in, _Float16* __restrict__ out,
                               int total4) {
    int i = blockIdx.x * blockDim.x + threadIdx.x;
    if (i >= total4) return;
    float4 v = reinterpret_cast<const float4*>(in)[i];
    half4 h;
    h.x = (_Float16)v.x; h.y = (_Float16)v.y; h.z = (_Float16)v.z; h.w = (_Float16)v.w;
    reinterpret_cast<half4*>(out)[i] = h;
}

// wT[n*K + k] = (f16) w[k*N + n]
__global__ void cvt_wT_kernel(const float* __restrict__ w, _Float16* __restrict__ wT,
                              int K, int N) {
    int i = blockIdx.x * blockDim.x + threadIdx.x;
    if (i >= K * N) return;
    int k = i / N, n = i - k * N;
    wT[(size_t)n * K + k] = (_Float16)w[i];
}

// ---------------- MFMA GEMM: C = A(f16 [M][K]) * BT(f16 [N][K])^T + bias ----------------
// BM=128. BN in {128, 64}. 256 threads = 4 waves in 2x2; each wave: 64 x (BN/2) region
// = 4 x WTN tiles of 16x16, MFMA 16x16x32 f16.
// LDS stride 40 halves (80B): frag ds_read_b128 bank-chunk = (5m+q) mod 8 -> conflict-free.

template<int KDIM, int NDIM, int BN>
__global__ __launch_bounds__(256) void gemm_mfma_kernel(
    const _Float16* __restrict__ A, const _Float16* __restrict__ BT,
    const float* __restrict__ bias, float* __restrict__ C, int M) {
    constexpr int BM = 128;
    constexpr int LDK = 40;
    constexpr int WTN = BN / 32;
    __shared__ _Float16 As[BM * LDK];
    __shared__ _Float16 Bs[BN * LDK];
    int t = threadIdx.x;
    int mbase = blockIdx.y * BM;
    int nbase = blockIdx.x * BN;
    int wv = t >> 6, lane = t & 63;
    int wm = (wv & 1) * 64;
    int wn = (wv >> 1) * (BN / 2);
    int q = lane >> 4;        // quad
    int fr = lane & 15;
    int sr = t >> 2;          // staging row 0..63
    int sc = (t & 3) * 8;     // staging k-offset (halves)

    floatx4 acc[4][WTN];
    for (int mt = 0; mt < 4; ++mt)
        for (int nt = 0; nt < WTN; ++nt)
            acc[mt][nt] = floatx4{0.f, 0.f, 0.f, 0.f};

    for (int k0 = 0; k0 < KDIM; k0 += 32) {
        // stage A (128 x 32)
        #pragma unroll
        for (int p = 0; p < 2; ++p) {
            int row = sr + p * 64;
            int grow = mbase + row;
            half8 v = {};
            if (grow < M)
                v = *reinterpret_cast<const half8*>(&A[(size_t)grow * KDIM + k0 + sc]);
            *reinterpret_cast<half8*>(&As[row * LDK + sc]) = v;
        }
        // stage B (BN x 32)
        #pragma unroll
        for (int p = 0; p < BN / 64; ++p) {
            int row = sr + p * 64;
            half8 v = *reinterpret_cast<const half8*>(&BT[(size_t)(nbase + row) * KDIM + k0 + sc]);
            *reinterpret_cast<half8*>(&Bs[row * LDK + sc]) = v;
        }
        __syncthreads();
        half8 af[4], bf[WTN];
        #pragma unroll
        for (int mt = 0; mt < 4; ++mt)
            af[mt] = *reinterpret_cast<const half8*>(&As[(wm + mt * 16 + fr) * LDK + q * 8]);
        #pragma unroll
        for (int nt = 0; nt < WTN; ++nt)
            bf[nt] = *reinterpret_cast<const half8*>(&Bs[(wn + nt * 16 + fr) * LDK + q * 8]);
        #pragma unroll
        for (int mt = 0; mt < 4; ++mt)
            #pragma unroll
            for (int nt = 0; nt < WTN; ++nt)
                acc[mt][nt] = __builtin_amdgcn_mfma_f32_16x16x32_f16(af[mt], bf[nt], acc[mt][nt], 0, 0, 0);
        __syncthreads();
    }
    // epilogue: D layout col = lane&15, row = (lane>>4)*4 + r
    #pragma unroll
    for (int nt = 0; nt < WTN; ++nt) {
        int col = nbase + wn + nt * 16 + fr;
        float bv = bias[col];
        #pragma unroll
        for (int mt = 0; mt < 4; ++mt) {
            #pragma unroll
            for (int r = 0; r < 4; ++r) {
                int row = mbase + wm + mt * 16 + q * 4 + r;
                if (row < M)
                    C[(size_t)row * NDIM + col] = acc[mt][nt][r] + bv;
            }
        }
    }
}

// ---------------- BatchNorm stats + apply (+GELU, f16 out) ----------------

__global__ void colstats_kernel(const float* __restrict__ T, float* __restrict__ sums, int M) {
    int col = threadIdx.x;               // 256 columns
    int r0 = blockIdx.x * 256;
    int r1 = min(r0 + 256, M);
    float s = 0.f, s2 = 0.f;
    for (int r = r0; r < r1; ++r) {
        float v = T[(size_t)r * N_H + col];
        s += v; s2 += v * v;
    }
    atomicAdd(&sums[col], s);
    atomicAdd(&sums[N_H + col], s2);
}

__global__ void finalize_stats_kernel(const float* __restrict__ sums,
                                      const float* __restrict__ g, const float* __restrict__ be,
                                      float* __restrict__ ab, float invM) {
    int c = threadIdx.x;
    float mean = sums[c] * invM;
    float var = sums[N_H + c] * invM - mean * mean;
    float a = g[c] * rsqrtf(var + EPS_BN);
    ab[c] = a;
    ab[N_H + c] = be[c] - mean * a;
}

__global__ void bn_gelu_kernel(const float* __restrict__ T, const float* __restrict__ ab,
                               const _Float16* __restrict__ res, _Float16* __restrict__ Y,
                               int total) {
    int i = blockIdx.x * blockDim.x + threadIdx.x;
    if (i >= total) return;
    int c = i & (N_H - 1);
    float v = ab[c] * T[i] + ab[N_H + c];
    if (res) v += (float)res[i];
    Y[i] = (_Float16)(0.5f * v * (1.f + erff(v * 0.70710678118654752f)));
}

// ---------------- Propagation ----------------

__global__ void prop_init_kernel(const float* __restrict__ h, const float* __restrict__ alpha,
                                 float* __restrict__ out, int total) {
    int i = blockIdx.x * blockDim.x + threadIdx.x;
    if (i < total) out[i] = h[i] * (alpha[0] * INV_TEMP);
}

// one wave per row, lane = feature (OUT=64); edge metadata scalarized, gathers 8-wide
__global__ __launch_bounds__(256) void prop_kernel(
    const float* __restrict__ xin, float* __restrict__ xout,
    const int2* __restrict__ ep, const int* __restrict__ row_ptr,
    const float* __restrict__ dinv, float* __restrict__ acc,
    const float* __restrict__ alpha, int kidx, int n) {
    int r = (blockIdx.x << 2) + (threadIdx.x >> 6);
    if (r >= n) return;
    int lane = threadIdx.x & 63;
    int s = __builtin_amdgcn_readfirstlane(row_ptr[r]);
    int e = __builtin_amdgcn_readfirstlane(row_ptr[r + 1]);
    float sum = 0.f;
    int i = s;
    for (; i + 8 <= e; i += 8) {
        int2 e0 = ep[i + 0], e1 = ep[i + 1], e2 = ep[i + 2], e3 = ep[i + 3];
        int2 e4 = ep[i + 4], e5 = ep[i + 5], e6 = ep[i + 6], e7 = ep[i + 7];
        float x0 = xin[((size_t)e0.x << 6) + lane];
        float x1 = xin[((size_t)e1.x << 6) + lane];
        float x2 = xin[((size_t)e2.x << 6) + lane];
        float x3 = xin[((size_t)e3.x << 6) + lane];
        float x4 = xin[((size_t)e4.x << 6) + lane];
        float x5 = xin[((size_t)e5.x << 6) + lane];
        float x6 = xin[((size_t)e6.x << 6) + lane];
        float x7 = xin[((size_t)e7.x << 6) + lane];
        sum += __int_as_float(e0.y) * x0 + __int_as_float(e1.y) * x1
             + __int_as_float(e2.y) * x2 + __int_as_float(e3.y) * x3
             + __int_as_float(e4.y) * x4 + __int_as_float(e5.y) * x5
             + __int_as_float(e6.y) * x6 + __int_as_float(e7.y) * x7;
    }
    for (; i < e; ++i) {
        int2 ee = ep[i];
        sum += __int_as_float(ee.y) * xin[((size_t)ee.x << 6) + lane];
    }
    float res = dinv[r] * sum;
    int o = (r << 6) + lane;
    xout[o] = res;
    acc[o] += (alpha[kidx] * INV_TEMP) * res;
}

// ---------------- Host ----------------

extern "C" void kernel_launch(void* const* d_in, const int* in_sizes, int n_in,
                              void* d_out, int out_size, void* d_ws, size_t ws_size,
                              hipStream_t stream) {
    const float* x    = (const float*)d_in[0];
    const int*   ei   = (const int*)d_in[1];
    const float* w1   = (const float*)d_in[2];
    const float* b1   = (const float*)d_in[3];
    const float* g1   = (const float*)d_in[4];
    const float* be1  = (const float*)d_in[5];
    const float* w2   = (const float*)d_in[6];
    const float* b2   = (const float*)d_in[7];
    const float* g2   = (const float*)d_in[8];
    const float* be2  = (const float*)d_in[9];
    const float* w3   = (const float*)d_in[10];
    const float* b3   = (const float*)d_in[11];
    const float* g3   = (const float*)d_in[12];
    const float* be3  = (const float*)d_in[13];
    const float* w4   = (const float*)d_in[14];
    const float* b4   = (const float*)d_in[15];
    const float* alpha= (const float*)d_in[16];
    float* out = (float*)d_out;

    const int N = in_sizes[0] / N_IN;     // 100000
    const int E = in_sizes[1] / 2;        // 3200000
    const int EN = E + N;

    char* ws = (char*)d_ws;
    size_t off = 0;
    auto alloc = [&](size_t bytes) -> void* {
        void* p = ws + off;
        off = (off + bytes + 255) & ~(size_t)255;
        return p;
    };
    int*   deg     = (int*)alloc((size_t)N * 4);
    int*   cursor  = (int*)alloc((size_t)N * 4);
    int*   row_ptr = (int*)alloc((size_t)(N + 1) * 4);
    float* dinv    = (float*)alloc((size_t)N * 4);
    int2*  ep      = (int2*)alloc((size_t)EN * 8);
    int*   bsum    = (int*)alloc(128 * 4);
    float* sums    = (float*)alloc(2 * N_H * 4);
    float* ab      = (float*)alloc(2 * N_H * 4);
    _Float16* w1T  = (_Float16*)alloc((size_t)N_IN * N_H * 2);
    _Float16* w2T  = (_Float16*)alloc((size_t)N_H * N_H * 2);
    _Float16* w3T  = (_Float16*)alloc((size_t)N_H * N_H * 2);
    _Float16* w4T  = (_Float16*)alloc((size_t)N_H * N_OUT * 2);
    _Float16* xh   = (_Float16*)alloc((size_t)N * N_IN * 2);
    float* T       = (float*)alloc((size_t)N * N_H * 4);    // GEMM out; reused as xt0/xt1
    _Float16* Ah0  = (_Float16*)alloc((size_t)N * N_H * 2);
    _Float16* Ah1  = (_Float16*)alloc((size_t)N * N_H * 2);
    float* hbuf    = (float*)alloc((size_t)N * N_OUT * 4);
    float* xt0 = T;
    float* xt1 = T + (size_t)N * N_OUT;

    const int TB = 256;
    int nbN  = (N + TB - 1) / TB;
    int nbE  = (E + TB - 1) / TB;
    int nbEN = (EN + TB - 1) / TB;
    int nscan = (N + 1023) / 1024;

    // --- CSR build ---
    init_kernel<<<nbN, TB, 0, stream>>>(deg, cursor, N);
    count_kernel<<<nbE, TB, 0, stream>>>(ei, deg, E);
    scan1_kernel<<<nscan, TB, 0, stream>>>(deg, row_ptr, bsum, N);
    scan2_kernel<<<1, 128, 0, stream>>>(bsum, nscan);
    scan3_kernel<<<nbN, TB, 0, stream>>>(row_ptr, bsum, deg, dinv, N, EN);
    fill_kernel<<<nbEN, TB, 0, stream>>>(ei, cursor, row_ptr, dinv, ep, E, N);

    // --- conversions ---
    int x4 = N * N_IN / 4;
    cvt_f16_kernel<<<(x4 + TB - 1) / TB, TB, 0, stream>>>(x, xh, x4);
    cvt_wT_kernel<<<(N_IN * N_H + TB - 1) / TB, TB, 0, stream>>>(w1, w1T, N_IN, N_H);
    cvt_wT_kernel<<<(N_H * N_H + TB - 1) / TB, TB, 0, stream>>>(w2, w2T, N_H, N_H);
    cvt_wT_kernel<<<(N_H * N_H + TB - 1) / TB, TB, 0, stream>>>(w3, w3T, N_H, N_H);
    cvt_wT_kernel<<<(N_H * N_OUT + TB - 1) / TB, TB, 0, stream>>>(w4, w4T, N_H, N_OUT);

    int mt = (N + 127) / 128;
    int elemH = N * N_H;
    int nbElemH = (elemH + TB - 1) / TB;
    int nbStats = (N + 255) / 256;

    // --- layer 1 ---
    gemm_mfma_kernel<N_IN, N_H, 128><<<dim3(N_H / 128, mt), TB, 0, stream>>>(xh, w1T, b1, T, N);
    hipMemsetAsync(sums, 0, 2 * N_H * 4, stream);
    colstats_kernel<<<nbStats, N_H, 0, stream>>>(T, sums, N);
    finalize_stats_kernel<<<1, N_H, 0, stream>>>(sums, g1, be1, ab, 1.0f / N);
    bn_gelu_kernel<<<nbElemH, TB, 0, stream>>>(T, ab, nullptr, Ah0, elemH);
    // --- layer 2 ---
    gemm_mfma_kernel<N_H, N_H, 128><<<dim3(N_H / 128, mt), TB, 0, stream>>>(Ah0, w2T, b2, T, N);
    hipMemsetAsync(sums, 0, 2 * N_H * 4, stream);
    colstats_kernel<<<nbStats, N_H, 0, stream>>>(T, sums, N);
    finalize_stats_kernel<<<1, N_H, 0, stream>>>(sums, g2, be2, ab, 1.0f / N);
    bn_gelu_kernel<<<nbElemH, TB, 0, stream>>>(T, ab, Ah0, Ah1, elemH);
    // --- layer 3 ---
    gemm_mfma_kernel<N_H, N_H, 128><<<dim3(N_H / 128, mt), TB, 0, stream>>>(Ah1, w3T, b3, T, N);
    hipMemsetAsync(sums, 0, 2 * N_H * 4, stream);
    colstats_kernel<<<nbStats, N_H, 0, stream>>>(T, sums, N);
    finalize_stats_kernel<<<1, N_H, 0, stream>>>(sums, g3, be3, ab, 1.0f / N);
    bn_gelu_kernel<<<nbElemH, TB, 0, stream>>>(T, ab, Ah1, Ah0, elemH);
    // --- layer 4 ---
    gemm_mfma_kernel<N_H, N_OUT, 64><<<dim3(1, mt), TB, 0, stream>>>(Ah0, w4T, b4, hbuf, N);

    // --- propagation ---
    int elemO = N * N_OUT;
    int nbElemO = (elemO + TB - 1) / TB;
    prop_init_kernel<<<nbElemO, TB, 0, stream>>>(hbuf, alpha, out, elemO);

    const float* cur = hbuf;
    float* pa = xt0;
    float* pb = xt1;
    int nbProp = (N + 3) / 4;
    for (int k = 1; k <= KHOP; ++k) {
        prop_kernel<<<nbProp, TB, 0, stream>>>(cur, pa, ep, row_ptr, dinv,
                                               out, alpha, k, N);
        cur = pa;
        float* tmp = pa; pa = pb; pb = tmp;
    }
}

// Round 3
// 1687.639 us; speedup vs baseline: 2.7880x; 1.3941x over previous
//
#include <hip/hip_runtime.h>
#include <math.h>

#define N_NODES 100000
#define N_IN 512
#define N_H 256
#define N_OUT 64
#define KHOP 10
#define EPS_BN 1e-5f
#define INV_TEMP (1.0f/1.5f)

using half8  = __attribute__((ext_vector_type(8))) _Float16;
using half4  = __attribute__((ext_vector_type(4))) _Float16;
using floatx4 = __attribute__((ext_vector_type(4))) float;

struct ZPtrs { const _Float16* p[KHOP]; };

// ---------------- CSR build ----------------

__global__ void init_kernel(int* __restrict__ deg, int* __restrict__ cursor, int n) {
    int i = blockIdx.x * blockDim.x + threadIdx.x;
    if (i < n) { deg[i] = 1; cursor[i] = 0; }   // deg starts at 1 for the self loop
}

__global__ void count_kernel(const int* __restrict__ ei, int* __restrict__ deg, int E) {
    int i = blockIdx.x * blockDim.x + threadIdx.x;
    if (i < E) atomicAdd(&deg[ei[i]], 1);
}

// block = 256 threads, each handles 4 elems -> 1024 per block
__global__ void scan1_kernel(const int* __restrict__ deg, int* __restrict__ excl,
                             int* __restrict__ bsum, int n) {
    __shared__ int sd[256];
    int t = threadIdx.x;
    int base = blockIdx.x * 1024 + t * 4;
    int v0 = (base + 0 < n) ? deg[base + 0] : 0;
    int v1 = (base + 1 < n) ? deg[base + 1] : 0;
    int v2 = (base + 2 < n) ? deg[base + 2] : 0;
    int v3 = (base + 3 < n) ? deg[base + 3] : 0;
    int tot = v0 + v1 + v2 + v3;
    sd[t] = tot;
    __syncthreads();
    for (int off = 1; off < 256; off <<= 1) {
        int x = (t >= off) ? sd[t - off] : 0;
        __syncthreads();
        sd[t] += x;
        __syncthreads();
    }
    int run = sd[t] - tot;   // exclusive
    if (t == 255) bsum[blockIdx.x] = sd[t];
    if (base + 0 < n) excl[base + 0] = run; run += v0;
    if (base + 1 < n) excl[base + 1] = run; run += v1;
    if (base + 2 < n) excl[base + 2] = run; run += v2;
    if (base + 3 < n) excl[base + 3] = run;
}

__global__ void scan2_kernel(int* __restrict__ bsum, int nb) {
    __shared__ int sd[128];
    int t = threadIdx.x;
    int v = (t < nb) ? bsum[t] : 0;
    sd[t] = v;
    __syncthreads();
    for (int off = 1; off < 128; off <<= 1) {
        int x = (t >= off) ? sd[t - off] : 0;
        __syncthreads();
        sd[t] += x;
        __syncthreads();
    }
    if (t < nb) bsum[t] = sd[t] - v;   // exclusive
}

__global__ void scan3_kernel(int* __restrict__ row_ptr, const int* __restrict__ bsum,
                             const int* __restrict__ deg, float* __restrict__ dinv,
                             float* __restrict__ dinv2, float* __restrict__ sqd,
                             int n, int total) {
    int i = blockIdx.x * blockDim.x + threadIdx.x;
    if (i < n) {
        row_ptr[i] += bsum[i >> 10];
        float d = (float)deg[i];
        dinv[i]  = rsqrtf(d);
        dinv2[i] = 1.0f / d;
        sqd[i]   = sqrtf(d);
    }
    if (i == 0) row_ptr[n] = total;
}

__global__ void fill_kernel(const int* __restrict__ ei, int* __restrict__ cursor,
                            const int* __restrict__ row_ptr,
                            int* __restrict__ colv, int E, int n) {
    int i = blockIdx.x * blockDim.x + threadIdx.x;
    if (i >= E + n) return;
    int r, c;
    if (i < E) { r = ei[i]; c = ei[E + i]; }
    else       { r = i - E; c = r; }
    int pos = row_ptr[r] + atomicAdd(&cursor[r], 1);
    colv[pos] = c;
}

// ---------------- conversions ----------------

__global__ void cvt_f16_kernel(const float* __restrict__ in, _Float16* __restrict__ out,
                               int total4) {
    int i = blockIdx.x * blockDim.x + threadIdx.x;
    if (i >= total4) return;
    float4 v = reinterpret_cast<const float4*>(in)[i];
    half4 h;
    h.x = (_Float16)v.x; h.y = (_Float16)v.y; h.z = (_Float16)v.z; h.w = (_Float16)v.w;
    reinterpret_cast<half4*>(out)[i] = h;
}

// wT[n*K + k] = (f16) w[k*N + n]
__global__ void cvt_wT_kernel(const float* __restrict__ w, _Float16* __restrict__ wT,
                              int K, int N) {
    int i = blockIdx.x * blockDim.x + threadIdx.x;
    if (i >= K * N) return;
    int k = i / N, n = i - k * N;
    wT[(size_t)n * K + k] = (_Float16)w[i];
}

// ---------------- MFMA GEMM: C = A(f16 [M][K]) * BT(f16 [N][K])^T + bias ----------------
// BM=128. BN in {128, 64}. 256 threads = 4 waves in 2x2; each wave: 64 x (BN/2) region
// = 4 x WTN tiles of 16x16, MFMA 16x16x32 f16.
// LDS stride 40 halves (80B): frag ds_read_b128 bank-chunk = (5m+q) mod 8 -> conflict-free.
// STATS: fused column sum/sumsq (BatchNorm) via LDS reduce + global atomics.
// WRITE_Z: also emit z0 = dinv[row] * C (f16) for the propagation stage.

template<int KDIM, int NDIM, int BN, bool STATS, bool WRITE_Z>
__global__ __launch_bounds__(256) void gemm_mfma_kernel(
    const _Float16* __restrict__ A, const _Float16* __restrict__ BT,
    const float* __restrict__ bias, float* __restrict__ C, int M,
    float* __restrict__ sums, const float* __restrict__ dinv,
    _Float16* __restrict__ z0) {
    constexpr int BM = 128;
    constexpr int LDK = 40;
    constexpr int WTN = BN / 32;
    __shared__ _Float16 As[BM * LDK];
    __shared__ _Float16 Bs[BN * LDK];
    __shared__ float cs[BN];
    __shared__ float cq[BN];
    int t = threadIdx.x;
    int mbase = blockIdx.y * BM;
    int nbase = blockIdx.x * BN;
    int wv = t >> 6, lane = t & 63;
    int wm = (wv & 1) * 64;
    int wn = (wv >> 1) * (BN / 2);
    int q = lane >> 4;        // quad
    int fr = lane & 15;
    int sr = t >> 2;          // staging row 0..63
    int sc = (t & 3) * 8;     // staging k-offset (halves)

    floatx4 acc[4][WTN];
    for (int mt = 0; mt < 4; ++mt)
        for (int nt = 0; nt < WTN; ++nt)
            acc[mt][nt] = floatx4{0.f, 0.f, 0.f, 0.f};

    for (int k0 = 0; k0 < KDIM; k0 += 32) {
        // stage A (128 x 32)
        #pragma unroll
        for (int p = 0; p < 2; ++p) {
            int row = sr + p * 64;
            int grow = mbase + row;
            half8 v = {};
            if (grow < M)
                v = *reinterpret_cast<const half8*>(&A[(size_t)grow * KDIM + k0 + sc]);
            *reinterpret_cast<half8*>(&As[row * LDK + sc]) = v;
        }
        // stage B (BN x 32)
        #pragma unroll
        for (int p = 0; p < BN / 64; ++p) {
            int row = sr + p * 64;
            half8 v = *reinterpret_cast<const half8*>(&BT[(size_t)(nbase + row) * KDIM + k0 + sc]);
            *reinterpret_cast<half8*>(&Bs[row * LDK + sc]) = v;
        }
        __syncthreads();
        half8 af[4], bf[WTN];
        #pragma unroll
        for (int mt = 0; mt < 4; ++mt)
            af[mt] = *reinterpret_cast<const half8*>(&As[(wm + mt * 16 + fr) * LDK + q * 8]);
        #pragma unroll
        for (int nt = 0; nt < WTN; ++nt)
            bf[nt] = *reinterpret_cast<const half8*>(&Bs[(wn + nt * 16 + fr) * LDK + q * 8]);
        #pragma unroll
        for (int mt = 0; mt < 4; ++mt)
            #pragma unroll
            for (int nt = 0; nt < WTN; ++nt)
                acc[mt][nt] = __builtin_amdgcn_mfma_f32_16x16x32_f16(af[mt], bf[nt], acc[mt][nt], 0, 0, 0);
        __syncthreads();
    }
    if constexpr (STATS) {
        if (t < BN) { cs[t] = 0.f; cq[t] = 0.f; }
        __syncthreads();
    }
    // epilogue: D layout col = lane&15, row = (lane>>4)*4 + r
    #pragma unroll
    for (int nt = 0; nt < WTN; ++nt) {
        int col = nbase + wn + nt * 16 + fr;
        float bv = bias[col];
        float s = 0.f, s2 = 0.f;
        #pragma unroll
        for (int mt = 0; mt < 4; ++mt) {
            #pragma unroll
            for (int rr = 0; rr < 4; ++rr) {
                int row = mbase + wm + mt * 16 + q * 4 + rr;
                if (row < M) {
                    float v = acc[mt][nt][rr] + bv;
                    C[(size_t)row * NDIM + col] = v;
                    if constexpr (STATS) { s += v; s2 += v * v; }
                    if constexpr (WRITE_Z)
                        z0[((size_t)row << 6) + col] = (_Float16)(dinv[row] * v);
                }
            }
        }
        if constexpr (STATS) {
            s  += __shfl_xor(s, 16);  s  += __shfl_xor(s, 32);
            s2 += __shfl_xor(s2, 16); s2 += __shfl_xor(s2, 32);
            if (q == 0) {
                atomicAdd(&cs[wn + nt * 16 + fr], s);
                atomicAdd(&cq[wn + nt * 16 + fr], s2);
            }
        }
    }
    if constexpr (STATS) {
        __syncthreads();
        if (t < BN) {
            atomicAdd(&sums[nbase + t], cs[t]);
            atomicAdd(&sums[N_H + nbase + t], cq[t]);
        }
    }
}

// ---------------- BatchNorm finalize + apply (+GELU, f16 out) ----------------

__global__ void finalize_stats_kernel(const float* __restrict__ sums,
                                      const float* __restrict__ g, const float* __restrict__ be,
                                      float* __restrict__ ab, float invM) {
    int c = threadIdx.x;
    float mean = sums[c] * invM;
    float var = sums[N_H + c] * invM - mean * mean;
    float a = g[c] * rsqrtf(var + EPS_BN);
    ab[c] = a;
    ab[N_H + c] = be[c] - mean * a;
}

__global__ void bn_gelu_kernel(const float* __restrict__ T, const float* __restrict__ ab,
                               const _Float16* __restrict__ res, _Float16* __restrict__ Y,
                               int total4) {
    int i = blockIdx.x * blockDim.x + threadIdx.x;
    if (i >= total4) return;
    int c0 = (i * 4) & (N_H - 1);
    float4 tv = reinterpret_cast<const float4*>(T)[i];
    float4 av = *reinterpret_cast<const float4*>(&ab[c0]);
    float4 bv = *reinterpret_cast<const float4*>(&ab[N_H + c0]);
    float v0 = av.x * tv.x + bv.x;
    float v1 = av.y * tv.y + bv.y;
    float v2 = av.z * tv.z + bv.z;
    float v3 = av.w * tv.w + bv.w;
    if (res) {
        half4 rv = reinterpret_cast<const half4*>(res)[i];
        v0 += (float)rv.x; v1 += (float)rv.y; v2 += (float)rv.z; v3 += (float)rv.w;
    }
    half4 o;
    o.x = (_Float16)(0.5f * v0 * (1.f + erff(v0 * 0.70710678118654752f)));
    o.y = (_Float16)(0.5f * v1 * (1.f + erff(v1 * 0.70710678118654752f)));
    o.z = (_Float16)(0.5f * v2 * (1.f + erff(v2 * 0.70710678118654752f)));
    o.w = (_Float16)(0.5f * v3 * (1.f + erff(v3 * 0.70710678118654752f)));
    reinterpret_cast<half4*>(Y)[i] = o;
}

// ---------------- Propagation ----------------
// z-substitution: z_k[r] = (1/deg[r]) * sum_{c in N(r)} z_{k-1}[c]; no per-edge weight.
// one wave per row, lane = feature (OUT=64), f16 state, f32 accumulate.

__global__ __launch_bounds__(256) void prop_kernel(
    const _Float16* __restrict__ zin, _Float16* __restrict__ zout,
    const int* __restrict__ colv, const int* __restrict__ row_ptr,
    const float* __restrict__ dinv2, int n) {
    int r = (blockIdx.x << 2) + (threadIdx.x >> 6);
    if (r >= n) return;
    int lane = threadIdx.x & 63;
    int s = __builtin_amdgcn_readfirstlane(row_ptr[r]);
    int e = __builtin_amdgcn_readfirstlane(row_ptr[r + 1]);
    float sum = 0.f;
    int i = s;
    for (; i + 8 <= e; i += 8) {
        int c0 = colv[i + 0], c1 = colv[i + 1], c2 = colv[i + 2], c3 = colv[i + 3];
        int c4 = colv[i + 4], c5 = colv[i + 5], c6 = colv[i + 6], c7 = colv[i + 7];
        float x0 = (float)zin[((size_t)c0 << 6) + lane];
        float x1 = (float)zin[((size_t)c1 << 6) + lane];
        float x2 = (float)zin[((size_t)c2 << 6) + lane];
        float x3 = (float)zin[((size_t)c3 << 6) + lane];
        float x4 = (float)zin[((size_t)c4 << 6) + lane];
        float x5 = (float)zin[((size_t)c5 << 6) + lane];
        float x6 = (float)zin[((size_t)c6 << 6) + lane];
        float x7 = (float)zin[((size_t)c7 << 6) + lane];
        sum += ((x0 + x1) + (x2 + x3)) + ((x4 + x5) + (x6 + x7));
    }
    for (; i < e; ++i)
        sum += (float)zin[((size_t)colv[i] << 6) + lane];
    float res = dinv2[r] * sum;
    zout[((size_t)r << 6) + lane] = (_Float16)res;
}

// out = INV_TEMP * (alpha0 * h + sqrt(deg[r]) * sum_k alpha_k * z_k)
__global__ void prop_final_kernel(const float* __restrict__ h, ZPtrs zp,
                                  const float* __restrict__ sqd,
                                  const float* __restrict__ alpha,
                                  float* __restrict__ out, int total4) {
    int i = blockIdx.x * blockDim.x + threadIdx.x;
    if (i >= total4) return;
    int r = i >> 4;                       // (i*4)/64
    float4 hv = reinterpret_cast<const float4*>(h)[i];
    float s0 = 0.f, s1 = 0.f, s2 = 0.f, s3 = 0.f;
    #pragma unroll
    for (int k = 0; k < KHOP; ++k) {
        half4 z = reinterpret_cast<const half4*>(zp.p[k])[i];
        float ak = alpha[k + 1];
        s0 += ak * (float)z.x; s1 += ak * (float)z.y;
        s2 += ak * (float)z.z; s3 += ak * (float)z.w;
    }
    float sq = sqd[r];
    float a0 = alpha[0];
    float4 o;
    o.x = INV_TEMP * (a0 * hv.x + sq * s0);
    o.y = INV_TEMP * (a0 * hv.y + sq * s1);
    o.z = INV_TEMP * (a0 * hv.z + sq * s2);
    o.w = INV_TEMP * (a0 * hv.w + sq * s3);
    reinterpret_cast<float4*>(out)[i] = o;
}

// ---------------- Host ----------------

extern "C" void kernel_launch(void* const* d_in, const int* in_sizes, int n_in,
                              void* d_out, int out_size, void* d_ws, size_t ws_size,
                              hipStream_t stream) {
    const float* x    = (const float*)d_in[0];
    const int*   ei   = (const int*)d_in[1];
    const float* w1   = (const float*)d_in[2];
    const float* b1   = (const float*)d_in[3];
    const float* g1   = (const float*)d_in[4];
    const float* be1  = (const float*)d_in[5];
    const float* w2   = (const float*)d_in[6];
    const float* b2   = (const float*)d_in[7];
    const float* g2   = (const float*)d_in[8];
    const float* be2  = (const float*)d_in[9];
    const float* w3   = (const float*)d_in[10];
    const float* b3   = (const float*)d_in[11];
    const float* g3   = (const float*)d_in[12];
    const float* be3  = (const float*)d_in[13];
    const float* w4   = (const float*)d_in[14];
    const float* b4   = (const float*)d_in[15];
    const float* alpha= (const float*)d_in[16];
    float* out = (float*)d_out;

    const int N = in_sizes[0] / N_IN;     // 100000
    const int E = in_sizes[1] / 2;        // 3200000
    const int EN = E + N;
    const size_t NZ = (size_t)N * N_OUT;  // elements per z buffer

    char* ws = (char*)d_ws;
    size_t off = 0;
    auto alloc = [&](size_t bytes) -> void* {
        void* p = ws + off;
        off = (off + bytes + 255) & ~(size_t)255;
        return p;
    };
    int*   deg     = (int*)alloc((size_t)N * 4);
    int*   cursor  = (int*)alloc((size_t)N * 4);
    int*   row_ptr = (int*)alloc((size_t)(N + 1) * 4);
    float* dinv    = (float*)alloc((size_t)N * 4);
    float* dinv2   = (float*)alloc((size_t)N * 4);
    float* sqd     = (float*)alloc((size_t)N * 4);
    int*   colv    = (int*)alloc((size_t)EN * 4);
    int*   bsum    = (int*)alloc(128 * 4);
    float* sums    = (float*)alloc(2 * N_H * 4);
    float* ab      = (float*)alloc(2 * N_H * 4);
    _Float16* w1T  = (_Float16*)alloc((size_t)N_IN * N_H * 2);
    _Float16* w2T  = (_Float16*)alloc((size_t)N_H * N_H * 2);
    _Float16* w3T  = (_Float16*)alloc((size_t)N_H * N_H * 2);
    _Float16* w4T  = (_Float16*)alloc((size_t)N_H * N_OUT * 2);
    _Float16* xh   = (_Float16*)alloc((size_t)N * N_IN * 2);
    float* T       = (float*)alloc((size_t)N * N_H * 4);    // GEMM out; reused as z1..z8
    _Float16* Ah0  = (_Float16*)alloc((size_t)N * N_H * 2); // x0 / x2
    _Float16* Ah1  = (_Float16*)alloc((size_t)N * N_H * 2); // x1; reused as z9,z10
    float* hbuf    = (float*)alloc((size_t)N * N_OUT * 4);
    _Float16* z0   = (_Float16*)alloc(NZ * 2);

    // z-buffer ring: z1..z8 live in T (8*12.8MB = 102.4MB = T exactly), z9,z10 in Ah1
    _Float16* zk[KHOP + 1];
    zk[0] = z0;
    for (int k = 1; k <= 8; ++k) zk[k] = (_Float16*)T + (size_t)(k - 1) * NZ;
    zk[9]  = (_Float16*)Ah1;
    zk[10] = (_Float16*)Ah1 + NZ;

    const int TB = 256;
    int nbN  = (N + TB - 1) / TB;
    int nbE  = (E + TB - 1) / TB;
    int nbEN = (EN + TB - 1) / TB;
    int nscan = (N + 1023) / 1024;

    // --- CSR build ---
    init_kernel<<<nbN, TB, 0, stream>>>(deg, cursor, N);
    count_kernel<<<nbE, TB, 0, stream>>>(ei, deg, E);
    scan1_kernel<<<nscan, TB, 0, stream>>>(deg, row_ptr, bsum, N);
    scan2_kernel<<<1, 128, 0, stream>>>(bsum, nscan);
    scan3_kernel<<<nbN, TB, 0, stream>>>(row_ptr, bsum, deg, dinv, dinv2, sqd, N, EN);
    fill_kernel<<<nbEN, TB, 0, stream>>>(ei, cursor, row_ptr, colv, E, N);

    // --- conversions ---
    int x4 = N * N_IN / 4;
    cvt_f16_kernel<<<(x4 + TB - 1) / TB, TB, 0, stream>>>(x, xh, x4);
    cvt_wT_kernel<<<(N_IN * N_H + TB - 1) / TB, TB, 0, stream>>>(w1, w1T, N_IN, N_H);
    cvt_wT_kernel<<<(N_H * N_H + TB - 1) / TB, TB, 0, stream>>>(w2, w2T, N_H, N_H);
    cvt_wT_kernel<<<(N_H * N_H + TB - 1) / TB, TB, 0, stream>>>(w3, w3T, N_H, N_H);
    cvt_wT_kernel<<<(N_H * N_OUT + TB - 1) / TB, TB, 0, stream>>>(w4, w4T, N_H, N_OUT);

    int mt = (N + 127) / 128;
    int elemH4 = N * N_H / 4;
    int nbElemH4 = (elemH4 + TB - 1) / TB;

    // --- layer 1 ---
    hipMemsetAsync(sums, 0, 2 * N_H * 4, stream);
    gemm_mfma_kernel<N_IN, N_H, 128, true, false><<<dim3(N_H / 128, mt), TB, 0, stream>>>(
        xh, w1T, b1, T, N, sums, nullptr, nullptr);
    finalize_stats_kernel<<<1, N_H, 0, stream>>>(sums, g1, be1, ab, 1.0f / N);
    bn_gelu_kernel<<<nbElemH4, TB, 0, stream>>>(T, ab, nullptr, Ah0, elemH4);
    // --- layer 2 ---
    hipMemsetAsync(sums, 0, 2 * N_H * 4, stream);
    gemm_mfma_kernel<N_H, N_H, 128, true, false><<<dim3(N_H / 128, mt), TB, 0, stream>>>(
        Ah0, w2T, b2, T, N, sums, nullptr, nullptr);
    finalize_stats_kernel<<<1, N_H, 0, stream>>>(sums, g2, be2, ab, 1.0f / N);
    bn_gelu_kernel<<<nbElemH4, TB, 0, stream>>>(T, ab, Ah0, Ah1, elemH4);
    // --- layer 3 ---
    hipMemsetAsync(sums, 0, 2 * N_H * 4, stream);
    gemm_mfma_kernel<N_H, N_H, 128, true, false><<<dim3(N_H / 128, mt), TB, 0, stream>>>(
        Ah1, w3T, b3, T, N, sums, nullptr, nullptr);
    finalize_stats_kernel<<<1, N_H, 0, stream>>>(sums, g3, be3, ab, 1.0f / N);
    bn_gelu_kernel<<<nbElemH4, TB, 0, stream>>>(T, ab, Ah1, Ah0, elemH4);
    // --- layer 4: h = x2 @ w4 + b4, plus z0 = dinv .* h (f16) ---
    gemm_mfma_kernel<N_H, N_OUT, 64, false, true><<<dim3(1, mt), TB, 0, stream>>>(
        Ah0, w4T, b4, hbuf, N, nullptr, dinv, z0);

    // --- propagation: z_k = D^{-1} A z_{k-1} ---
    int nbProp = (N + 3) / 4;
    for (int k = 1; k <= KHOP; ++k) {
        prop_kernel<<<nbProp, TB, 0, stream>>>(zk[k - 1], zk[k], colv, row_ptr, dinv2, N);
    }

    // --- final accumulation ---
    ZPtrs zp;
    for (int k = 0; k < KHOP; ++k) zp.p[k] = zk[k + 1];
    int total4 = N * N_OUT / 4;
    prop_final_kernel<<<(total4 + TB - 1) / TB, TB, 0, stream>>>(hbuf, zp, sqd, alpha, out, total4);
}

// Round 4
// 1641.328 us; speedup vs baseline: 2.8667x; 1.0282x over previous
//
#include <hip/hip_runtime.h>
#include <math.h>

#define N_NODES 100000
#define N_IN 512
#define N_H 256
#define N_OUT 64
#define KHOP 10
#define EPS_BN 1e-5f
#define INV_TEMP (1.0f/1.5f)

using half8  = __attribute__((ext_vector_type(8))) _Float16;
using half4  = __attribute__((ext_vector_type(4))) _Float16;
using floatx4 = __attribute__((ext_vector_type(4))) float;

struct ZPtrs { const _Float16* p[KHOP]; };

// ---------------- CSR build ----------------

__global__ void init_kernel(int* __restrict__ deg, int* __restrict__ cursor, int n) {
    int i = blockIdx.x * blockDim.x + threadIdx.x;
    if (i < n) { deg[i] = 1; cursor[i] = 0; }   // deg starts at 1 for the self loop
}

__global__ void count_kernel(const int* __restrict__ ei, int* __restrict__ deg, int E) {
    int i = blockIdx.x * blockDim.x + threadIdx.x;
    if (i < E) atomicAdd(&deg[ei[i]], 1);
}

// block = 256 threads, each handles 4 elems -> 1024 per block
__global__ void scan1_kernel(const int* __restrict__ deg, int* __restrict__ excl,
                             int* __restrict__ bsum, int n) {
    __shared__ int sd[256];
    int t = threadIdx.x;
    int base = blockIdx.x * 1024 + t * 4;
    int v0 = (base + 0 < n) ? deg[base + 0] : 0;
    int v1 = (base + 1 < n) ? deg[base + 1] : 0;
    int v2 = (base + 2 < n) ? deg[base + 2] : 0;
    int v3 = (base + 3 < n) ? deg[base + 3] : 0;
    int tot = v0 + v1 + v2 + v3;
    sd[t] = tot;
    __syncthreads();
    for (int off = 1; off < 256; off <<= 1) {
        int x = (t >= off) ? sd[t - off] : 0;
        __syncthreads();
        sd[t] += x;
        __syncthreads();
    }
    int run = sd[t] - tot;   // exclusive
    if (t == 255) bsum[blockIdx.x] = sd[t];
    if (base + 0 < n) excl[base + 0] = run; run += v0;
    if (base + 1 < n) excl[base + 1] = run; run += v1;
    if (base + 2 < n) excl[base + 2] = run; run += v2;
    if (base + 3 < n) excl[base + 3] = run;
}

__global__ void scan2_kernel(int* __restrict__ bsum, int nb) {
    __shared__ int sd[128];
    int t = threadIdx.x;
    int v = (t < nb) ? bsum[t] : 0;
    sd[t] = v;
    __syncthreads();
    for (int off = 1; off < 128; off <<= 1) {
        int x = (t >= off) ? sd[t - off] : 0;
        __syncthreads();
        sd[t] += x;
        __syncthreads();
    }
    if (t < nb) bsum[t] = sd[t] - v;   // exclusive
}

__global__ void scan3_kernel(int* __restrict__ row_ptr, const int* __restrict__ bsum,
                             const int* __restrict__ deg, float* __restrict__ dinv,
                             float* __restrict__ dinv2, float* __restrict__ sqd,
                             int n, int total) {
    int i = blockIdx.x * blockDim.x + threadIdx.x;
    if (i < n) {
        row_ptr[i] += bsum[i >> 10];
        float d = (float)deg[i];
        dinv[i]  = rsqrtf(d);
        dinv2[i] = 1.0f / d;
        sqd[i]   = sqrtf(d);
    }
    if (i == 0) row_ptr[n] = total;
}

// bucketed fill: only rows in [r0, r1) handled this pass -> scatter-write window
// is ~3.4 MB (L2-resident), breaking the 64B dirty-line thrash.
__global__ void fill_kernel(const int* __restrict__ ei, int* __restrict__ cursor,
                            const int* __restrict__ row_ptr,
                            int* __restrict__ colv, int E, int n, int r0, int r1) {
    int i = blockIdx.x * blockDim.x + threadIdx.x;
    if (i >= E + n) return;
    int r, c;
    if (i < E) { r = ei[i]; c = ei[E + i]; }
    else       { r = i - E; c = r; }
    if (r < r0 || r >= r1) return;
    int pos = row_ptr[r] + atomicAdd(&cursor[r], 1);
    colv[pos] = c;
}

// ---------------- conversions ----------------

__global__ void cvt_f16_kernel(const float* __restrict__ in, _Float16* __restrict__ out,
                               int total4) {
    int i = blockIdx.x * blockDim.x + threadIdx.x;
    if (i >= total4) return;
    float4 v = reinterpret_cast<const float4*>(in)[i];
    half4 h;
    h.x = (_Float16)v.x; h.y = (_Float16)v.y; h.z = (_Float16)v.z; h.w = (_Float16)v.w;
    reinterpret_cast<half4*>(out)[i] = h;
}

// wT[n*K + k] = (f16) w[k*N + n]
__global__ void cvt_wT_kernel(const float* __restrict__ w, _Float16* __restrict__ wT,
                              int K, int N) {
    int i = blockIdx.x * blockDim.x + threadIdx.x;
    if (i >= K * N) return;
    int k = i / N, n = i - k * N;
    wT[(size_t)n * K + k] = (_Float16)w[i];
}

// ---------------- MFMA GEMM: C = A(f16 [M][K]) * BT(f16 [N][K])^T + bias ----------------
// BM=128. BN in {128, 64}. 256 threads = 4 waves in 2x2; each wave: 64 x (BN/2) region
// = 4 x WTN tiles of 16x16, MFMA 16x16x32 f16.
// LDS stride 40 halves (80B): frag ds_read_b128 bank-chunk = (5m+q) mod 8 -> conflict-free.
// STATS: fused column sum/sumsq (BatchNorm, from f32 accums) via LDS reduce + atomics.
// WRITE_Z: also emit z0 = dinv[row] * C (f16). CT: output element type.

template<int KDIM, int NDIM, int BN, bool STATS, bool WRITE_Z, typename CT>
__global__ __launch_bounds__(256) void gemm_mfma_kernel(
    const _Float16* __restrict__ A, const _Float16* __restrict__ BT,
    const float* __restrict__ bias, CT* __restrict__ C, int M,
    float* __restrict__ sums, const float* __restrict__ dinv,
    _Float16* __restrict__ z0) {
    constexpr int BM = 128;
    constexpr int LDK = 40;
    constexpr int WTN = BN / 32;
    __shared__ _Float16 As[BM * LDK];
    __shared__ _Float16 Bs[BN * LDK];
    __shared__ float cs[BN];
    __shared__ float cq[BN];
    int t = threadIdx.x;
    int mbase = blockIdx.y * BM;
    int nbase = blockIdx.x * BN;
    int wv = t >> 6, lane = t & 63;
    int wm = (wv & 1) * 64;
    int wn = (wv >> 1) * (BN / 2);
    int q = lane >> 4;        // quad
    int fr = lane & 15;
    int sr = t >> 2;          // staging row 0..63
    int sc = (t & 3) * 8;     // staging k-offset (halves)

    floatx4 acc[4][WTN];
    for (int mt = 0; mt < 4; ++mt)
        for (int nt = 0; nt < WTN; ++nt)
            acc[mt][nt] = floatx4{0.f, 0.f, 0.f, 0.f};

    for (int k0 = 0; k0 < KDIM; k0 += 32) {
        #pragma unroll
        for (int p = 0; p < 2; ++p) {
            int row = sr + p * 64;
            int grow = mbase + row;
            half8 v = {};
            if (grow < M)
                v = *reinterpret_cast<const half8*>(&A[(size_t)grow * KDIM + k0 + sc]);
            *reinterpret_cast<half8*>(&As[row * LDK + sc]) = v;
        }
        #pragma unroll
        for (int p = 0; p < BN / 64; ++p) {
            int row = sr + p * 64;
            half8 v = *reinterpret_cast<const half8*>(&BT[(size_t)(nbase + row) * KDIM + k0 + sc]);
            *reinterpret_cast<half8*>(&Bs[row * LDK + sc]) = v;
        }
        __syncthreads();
        half8 af[4], bf[WTN];
        #pragma unroll
        for (int mt = 0; mt < 4; ++mt)
            af[mt] = *reinterpret_cast<const half8*>(&As[(wm + mt * 16 + fr) * LDK + q * 8]);
        #pragma unroll
        for (int nt = 0; nt < WTN; ++nt)
            bf[nt] = *reinterpret_cast<const half8*>(&Bs[(wn + nt * 16 + fr) * LDK + q * 8]);
        #pragma unroll
        for (int mt = 0; mt < 4; ++mt)
            #pragma unroll
            for (int nt = 0; nt < WTN; ++nt)
                acc[mt][nt] = __builtin_amdgcn_mfma_f32_16x16x32_f16(af[mt], bf[nt], acc[mt][nt], 0, 0, 0);
        __syncthreads();
    }
    if constexpr (STATS) {
        if (t < BN) { cs[t] = 0.f; cq[t] = 0.f; }
        __syncthreads();
    }
    // epilogue: D layout col = lane&15, row = (lane>>4)*4 + r
    #pragma unroll
    for (int nt = 0; nt < WTN; ++nt) {
        int col = nbase + wn + nt * 16 + fr;
        float bv = bias[col];
        float s = 0.f, s2 = 0.f;
        #pragma unroll
        for (int mt = 0; mt < 4; ++mt) {
            #pragma unroll
            for (int rr = 0; rr < 4; ++rr) {
                int row = mbase + wm + mt * 16 + q * 4 + rr;
                if (row < M) {
                    float v = acc[mt][nt][rr] + bv;
                    C[(size_t)row * NDIM + col] = (CT)v;
                    if constexpr (STATS) { s += v; s2 += v * v; }
                    if constexpr (WRITE_Z)
                        z0[((size_t)row << 6) + col] = (_Float16)(dinv[row] * v);
                }
            }
        }
        if constexpr (STATS) {
            s  += __shfl_xor(s, 16);  s  += __shfl_xor(s, 32);
            s2 += __shfl_xor(s2, 16); s2 += __shfl_xor(s2, 32);
            if (q == 0) {
                atomicAdd(&cs[wn + nt * 16 + fr], s);
                atomicAdd(&cq[wn + nt * 16 + fr], s2);
            }
        }
    }
    if constexpr (STATS) {
        __syncthreads();
        if (t < BN) {
            atomicAdd(&sums[nbase + t], cs[t]);
            atomicAdd(&sums[N_H + nbase + t], cq[t]);
        }
    }
}

// ---------------- BatchNorm finalize + apply (+GELU, f16 out) ----------------

__global__ void finalize_stats_kernel(const float* __restrict__ sums,
                                      const float* __restrict__ g, const float* __restrict__ be,
                                      float* __restrict__ ab, float invM) {
    int c = threadIdx.x;
    float mean = sums[c] * invM;
    float var = sums[N_H + c] * invM - mean * mean;
    float a = g[c] * rsqrtf(var + EPS_BN);
    ab[c] = a;
    ab[N_H + c] = be[c] - mean * a;
}

__global__ void bn_gelu_kernel(const _Float16* __restrict__ T, const float* __restrict__ ab,
                               const _Float16* __restrict__ res, _Float16* __restrict__ Y,
                               int total4) {
    int i = blockIdx.x * blockDim.x + threadIdx.x;
    if (i >= total4) return;
    int c0 = (i * 4) & (N_H - 1);
    half4 tv = reinterpret_cast<const half4*>(T)[i];
    float4 av = *reinterpret_cast<const float4*>(&ab[c0]);
    float4 bv = *reinterpret_cast<const float4*>(&ab[N_H + c0]);
    float v0 = av.x * (float)tv.x + bv.x;
    float v1 = av.y * (float)tv.y + bv.y;
    float v2 = av.z * (float)tv.z + bv.z;
    float v3 = av.w * (float)tv.w + bv.w;
    if (res) {
        half4 rv = reinterpret_cast<const half4*>(res)[i];
        v0 += (float)rv.x; v1 += (float)rv.y; v2 += (float)rv.z; v3 += (float)rv.w;
    }
    half4 o;
    o.x = (_Float16)(0.5f * v0 * (1.f + erff(v0 * 0.70710678118654752f)));
    o.y = (_Float16)(0.5f * v1 * (1.f + erff(v1 * 0.70710678118654752f)));
    o.z = (_Float16)(0.5f * v2 * (1.f + erff(v2 * 0.70710678118654752f)));
    o.w = (_Float16)(0.5f * v3 * (1.f + erff(v3 * 0.70710678118654752f)));
    reinterpret_cast<half4*>(Y)[i] = o;
}

// ---------------- Propagation ----------------
// z_k[r] = (1/deg[r]) * sum_{c in N(r)} z_{k-1}[c].  One wave per row; wave
// covers 4 edges at once: lane = 16*esub + fq, each lane loads half4 (8B).
// Reduction over esub groups via shfl_xor(16/32); lanes 0..15 write the row.

__global__ __launch_bounds__(256) void prop_kernel(
    const _Float16* __restrict__ zin, _Float16* __restrict__ zout,
    const int* __restrict__ colv, const int* __restrict__ row_ptr,
    const float* __restrict__ dinv2, int n) {
    int r = (blockIdx.x << 2) + (threadIdx.x >> 6);
    if (r >= n) return;
    int lane = threadIdx.x & 63;
    int esub = lane >> 4;       // 0..3
    int fo = (lane & 15) << 2;  // feature offset 0..60
    int s = __builtin_amdgcn_readfirstlane(row_ptr[r]);
    int e = __builtin_amdgcn_readfirstlane(row_ptr[r + 1]);
    float a0 = 0.f, a1 = 0.f, a2 = 0.f, a3 = 0.f;
    int i = s;
    for (; i + 16 <= e; i += 16) {
        int c0 = colv[i + esub];
        int c1 = colv[i + 4 + esub];
        int c2 = colv[i + 8 + esub];
        int c3 = colv[i + 12 + esub];
        half4 v0 = *reinterpret_cast<const half4*>(&zin[((size_t)c0 << 6) + fo]);
        half4 v1 = *reinterpret_cast<const half4*>(&zin[((size_t)c1 << 6) + fo]);
        half4 v2 = *reinterpret_cast<const half4*>(&zin[((size_t)c2 << 6) + fo]);
        half4 v3 = *reinterpret_cast<const half4*>(&zin[((size_t)c3 << 6) + fo]);
        a0 += (float)v0.x + (float)v1.x + (float)v2.x + (float)v3.x;
        a1 += (float)v0.y + (float)v1.y + (float)v2.y + (float)v3.y;
        a2 += (float)v0.z + (float)v1.z + (float)v2.z + (float)v3.z;
        a3 += (float)v0.w + (float)v1.w + (float)v2.w + (float)v3.w;
    }
    for (; i + 4 <= e; i += 4) {
        int c = colv[i + esub];
        half4 v = *reinterpret_cast<const half4*>(&zin[((size_t)c << 6) + fo]);
        a0 += (float)v.x; a1 += (float)v.y; a2 += (float)v.z; a3 += (float)v.w;
    }
    int rem = e - i;
    if (esub < rem) {
        int c = colv[i + esub];
        half4 v = *reinterpret_cast<const half4*>(&zin[((size_t)c << 6) + fo]);
        a0 += (float)v.x; a1 += (float)v.y; a2 += (float)v.z; a3 += (float)v.w;
    }
    a0 += __shfl_xor(a0, 16); a1 += __shfl_xor(a1, 16);
    a2 += __shfl_xor(a2, 16); a3 += __shfl_xor(a3, 16);
    a0 += __shfl_xor(a0, 32); a1 += __shfl_xor(a1, 32);
    a2 += __shfl_xor(a2, 32); a3 += __shfl_xor(a3, 32);
    if (lane < 16) {
        float d = dinv2[r];
        half4 o;
        o.x = (_Float16)(a0 * d); o.y = (_Float16)(a1 * d);
        o.z = (_Float16)(a2 * d); o.w = (_Float16)(a3 * d);
        *reinterpret_cast<half4*>(&zout[((size_t)r << 6) + fo]) = o;
    }
}

// out = INV_TEMP * (alpha0 * h + sqrt(deg[r]) * sum_k alpha_k * z_k)
__global__ void prop_final_kernel(const float* __restrict__ h, ZPtrs zp,
                                  const float* __restrict__ sqd,
                                  const float* __restrict__ alpha,
                                  float* __restrict__ out, int total4) {
    int i = blockIdx.x * blockDim.x + threadIdx.x;
    if (i >= total4) return;
    int r = i >> 4;                       // (i*4)/64
    float4 hv = reinterpret_cast<const float4*>(h)[i];
    float s0 = 0.f, s1 = 0.f, s2 = 0.f, s3 = 0.f;
    #pragma unroll
    for (int k = 0; k < KHOP; ++k) {
        half4 z = reinterpret_cast<const half4*>(zp.p[k])[i];
        float ak = alpha[k + 1];
        s0 += ak * (float)z.x; s1 += ak * (float)z.y;
        s2 += ak * (float)z.z; s3 += ak * (float)z.w;
    }
    float sq = sqd[r];
    float a0 = alpha[0];
    float4 o;
    o.x = INV_TEMP * (a0 * hv.x + sq * s0);
    o.y = INV_TEMP * (a0 * hv.y + sq * s1);
    o.z = INV_TEMP * (a0 * hv.z + sq * s2);
    o.w = INV_TEMP * (a0 * hv.w + sq * s3);
    reinterpret_cast<float4*>(out)[i] = o;
}

// ---------------- Host ----------------

extern "C" void kernel_launch(void* const* d_in, const int* in_sizes, int n_in,
                              void* d_out, int out_size, void* d_ws, size_t ws_size,
                              hipStream_t stream) {
    const float* x    = (const float*)d_in[0];
    const int*   ei   = (const int*)d_in[1];
    const float* w1   = (const float*)d_in[2];
    const float* b1   = (const float*)d_in[3];
    const float* g1   = (const float*)d_in[4];
    const float* be1  = (const float*)d_in[5];
    const float* w2   = (const float*)d_in[6];
    const float* b2   = (const float*)d_in[7];
    const float* g2   = (const float*)d_in[8];
    const float* be2  = (const float*)d_in[9];
    const float* w3   = (const float*)d_in[10];
    const float* b3   = (const float*)d_in[11];
    const float* g3   = (const float*)d_in[12];
    const float* be3  = (const float*)d_in[13];
    const float* w4   = (const float*)d_in[14];
    const float* b4   = (const float*)d_in[15];
    const float* alpha= (const float*)d_in[16];
    float* out = (float*)d_out;

    const int N = in_sizes[0] / N_IN;     // 100000
    const int E = in_sizes[1] / 2;        // 3200000
    const int EN = E + N;
    const size_t NZ = (size_t)N * N_OUT;  // elements per z buffer

    char* ws = (char*)d_ws;
    size_t off = 0;
    auto alloc = [&](size_t bytes) -> void* {
        void* p = ws + off;
        off = (off + bytes + 255) & ~(size_t)255;
        return p;
    };
    int*   deg     = (int*)alloc((size_t)N * 4);
    int*   cursor  = (int*)alloc((size_t)N * 4);
    int*   row_ptr = (int*)alloc((size_t)(N + 1) * 4);
    float* dinv    = (float*)alloc((size_t)N * 4);
    float* dinv2   = (float*)alloc((size_t)N * 4);
    float* sqd     = (float*)alloc((size_t)N * 4);
    int*   colv    = (int*)alloc((size_t)EN * 4);
    int*   bsum    = (int*)alloc(128 * 4);
    float* sums    = (float*)alloc(2 * N_H * 4);
    float* ab      = (float*)alloc(2 * N_H * 4);
    _Float16* w1T  = (_Float16*)alloc((size_t)N_IN * N_H * 2);
    _Float16* w2T  = (_Float16*)alloc((size_t)N_H * N_H * 2);
    _Float16* w3T  = (_Float16*)alloc((size_t)N_H * N_H * 2);
    _Float16* w4T  = (_Float16*)alloc((size_t)N_H * N_OUT * 2);
    _Float16* xh   = (_Float16*)alloc((size_t)N * N_IN * 2);
    float* T       = (float*)alloc((size_t)N * N_H * 4);    // f16 GEMM out (first half); reused as z1..z8
    _Float16* Ah0  = (_Float16*)alloc((size_t)N * N_H * 2); // x0 / x2
    _Float16* Ah1  = (_Float16*)alloc((size_t)N * N_H * 2); // x1; reused as z9,z10
    float* hbuf    = (float*)alloc((size_t)N * N_OUT * 4);
    _Float16* z0   = (_Float16*)alloc(NZ * 2);

    _Float16* Tf16 = (_Float16*)T;

    // z-buffer ring: z1..z8 live in T region (8*12.8MB), z9,z10 in Ah1
    _Float16* zk[KHOP + 1];
    zk[0] = z0;
    for (int k = 1; k <= 8; ++k) zk[k] = (_Float16*)T + (size_t)(k - 1) * NZ;
    zk[9]  = (_Float16*)Ah1;
    zk[10] = (_Float16*)Ah1 + NZ;

    const int TB = 256;
    int nbN  = (N + TB - 1) / TB;
    int nbE  = (E + TB - 1) / TB;
    int nbEN = (EN + TB - 1) / TB;
    int nscan = (N + 1023) / 1024;

    // --- CSR build ---
    init_kernel<<<nbN, TB, 0, stream>>>(deg, cursor, N);
    count_kernel<<<nbE, TB, 0, stream>>>(ei, deg, E);
    scan1_kernel<<<nscan, TB, 0, stream>>>(deg, row_ptr, bsum, N);
    scan2_kernel<<<1, 128, 0, stream>>>(bsum, nscan);
    scan3_kernel<<<nbN, TB, 0, stream>>>(row_ptr, bsum, deg, dinv, dinv2, sqd, N, EN);
    {
        const int P = 4;
        int step = (N + P - 1) / P;
        for (int p = 0; p < P; ++p) {
            int r0 = p * step;
            int r1 = min(N, r0 + step);
            fill_kernel<<<nbEN, TB, 0, stream>>>(ei, cursor, row_ptr, colv, E, N, r0, r1);
        }
    }

    // --- conversions ---
    int x4 = N * N_IN / 4;
    cvt_f16_kernel<<<(x4 + TB - 1) / TB, TB, 0, stream>>>(x, xh, x4);
    cvt_wT_kernel<<<(N_IN * N_H + TB - 1) / TB, TB, 0, stream>>>(w1, w1T, N_IN, N_H);
    cvt_wT_kernel<<<(N_H * N_H + TB - 1) / TB, TB, 0, stream>>>(w2, w2T, N_H, N_H);
    cvt_wT_kernel<<<(N_H * N_H + TB - 1) / TB, TB, 0, stream>>>(w3, w3T, N_H, N_H);
    cvt_wT_kernel<<<(N_H * N_OUT + TB - 1) / TB, TB, 0, stream>>>(w4, w4T, N_H, N_OUT);

    int mt = (N + 127) / 128;
    int elemH4 = N * N_H / 4;
    int nbElemH4 = (elemH4 + TB - 1) / TB;

    // --- layer 1 ---
    hipMemsetAsync(sums, 0, 2 * N_H * 4, stream);
    gemm_mfma_kernel<N_IN, N_H, 128, true, false, _Float16><<<dim3(N_H / 128, mt), TB, 0, stream>>>(
        xh, w1T, b1, Tf16, N, sums, nullptr, nullptr);
    finalize_stats_kernel<<<1, N_H, 0, stream>>>(sums, g1, be1, ab, 1.0f / N);
    bn_gelu_kernel<<<nbElemH4, TB, 0, stream>>>(Tf16, ab, nullptr, Ah0, elemH4);
    // --- layer 2 ---
    hipMemsetAsync(sums, 0, 2 * N_H * 4, stream);
    gemm_mfma_kernel<N_H, N_H, 128, true, false, _Float16><<<dim3(N_H / 128, mt), TB, 0, stream>>>(
        Ah0, w2T, b2, Tf16, N, sums, nullptr, nullptr);
    finalize_stats_kernel<<<1, N_H, 0, stream>>>(sums, g2, be2, ab, 1.0f / N);
    bn_gelu_kernel<<<nbElemH4, TB, 0, stream>>>(Tf16, ab, Ah0, Ah1, elemH4);
    // --- layer 3 ---
    hipMemsetAsync(sums, 0, 2 * N_H * 4, stream);
    gemm_mfma_kernel<N_H, N_H, 128, true, false, _Float16><<<dim3(N_H / 128, mt), TB, 0, stream>>>(
        Ah1, w3T, b3, Tf16, N, sums, nullptr, nullptr);
    finalize_stats_kernel<<<1, N_H, 0, stream>>>(sums, g3, be3, ab, 1.0f / N);
    bn_gelu_kernel<<<nbElemH4, TB, 0, stream>>>(Tf16, ab, Ah1, Ah0, elemH4);
    // --- layer 4: h = x2 @ w4 + b4 (f32), plus z0 = dinv .* h (f16) ---
    gemm_mfma_kernel<N_H, N_OUT, 64, false, true, float><<<dim3(1, mt), TB, 0, stream>>>(
        Ah0, w4T, b4, hbuf, N, nullptr, dinv, z0);

    // --- propagation: z_k = D^{-1} A z_{k-1} ---
    int nbProp = (N + 3) / 4;
    for (int k = 1; k <= KHOP; ++k) {
        prop_kernel<<<nbProp, TB, 0, stream>>>(zk[k - 1], zk[k], colv, row_ptr, dinv2, N);
    }

    // --- final accumulation ---
    ZPtrs zp;
    for (int k = 0; k < KHOP; ++k) zp.p[k] = zk[k + 1];
    int total4 = N * N_OUT / 4;
    prop_final_kernel<<<(total4 + TB - 1) / TB, TB, 0, stream>>>(hbuf, zp, sqd, alpha, out, total4);
}